// Round 7
// baseline (172.336 us; speedup 1.0000x reference)
//
#include <hip/hip_runtime.h>

#define NBATCH 2
#define NPTS   16384
#define NTILES 1024              // NPTS / 16
#define JCH    16                // col-chunks per n
#define NT_PER (NTILES / JCH)    // 64 col-tiles per block
#define MB     32                // row-blocks per n
#define MW     8                 // row-tiles per wave (block = 4 waves = 32 row-tiles)

typedef float f32x4 __attribute__((ext_vector_type(4)));
typedef short s16x8 __attribute__((ext_vector_type(8)));

__device__ __forceinline__ unsigned short f2bf(float f) {   // RTNE, finite inputs
    unsigned u = __float_as_uint(f);
    u += 0x7FFF + ((u >> 16) & 1);
    return (unsigned short)(u >> 16);
}
__device__ __forceinline__ float bf2f(unsigned short h) {
    return __uint_as_float((unsigned)h << 16);
}

// Build MFMA-ready K=32 panels for ONE direction (A = srcA cloud, B = srcB).
// A-side slots: [ah(3) | al(3) | ah(3) | al(3) | 1 1 1 | sqa_h sqa_m sqa_l | 0..]
// B-side slots: [-2bh(3)| -2bh(3)| -2bl(3)| -2bl(3)| sqb_h sqb_m sqb_l | 1 1 1 | 0..]
// dot_k = sqa + sqb - 2*(ah+al)·(bh+bl)  (4 cross terms; approx err ~1e-4 worst)
__global__ __launch_bounds__(256) void pack_panels(
    const float* __restrict__ srcA, const float* __restrict__ srcB,
    unsigned short* __restrict__ apan, unsigned short* __restrict__ bpan)
{
    int tid = blockIdx.x * 256 + threadIdx.x;   // 2^18 threads
    int lane = tid & 63;
    int tile = (tid >> 6) & (NTILES - 1);
    int n    = (tid >> 16) & 1;
    int whichB = (tid >> 17) & 1;

    const float* src = whichB ? srcB : srcA;

    int p = tile * 16 + (lane & 15);
    const float* q = src + ((size_t)n * NPTS + p) * 3;
    float x = q[0], y = q[1], z = q[2];

    unsigned short xh = f2bf(x), yh = f2bf(y), zh = f2bf(z);
    unsigned short xl = f2bf(x - bf2f(xh)), yl = f2bf(y - bf2f(yh)), zl = f2bf(z - bf2f(zh));
    float sq = x * x + y * y + z * z;
    unsigned short sh = f2bf(sq);  float r1 = sq - bf2f(sh);
    unsigned short sm = f2bf(r1);  float r2 = r1 - bf2f(sm);
    unsigned short sl = f2bf(r2);
    const unsigned short one = 0x3F80;

    unsigned short slots[18];
    if (!whichB) {
        slots[0]=xh;  slots[1]=yh;  slots[2]=zh;
        slots[3]=xl;  slots[4]=yl;  slots[5]=zl;
        slots[6]=xh;  slots[7]=yh;  slots[8]=zh;
        slots[9]=xl;  slots[10]=yl; slots[11]=zl;
        slots[12]=one; slots[13]=one; slots[14]=one;
        slots[15]=sh;  slots[16]=sm;  slots[17]=sl;
    } else {
        unsigned short mxh=f2bf(-2.f*bf2f(xh)), myh=f2bf(-2.f*bf2f(yh)), mzh=f2bf(-2.f*bf2f(zh));
        unsigned short mxl=f2bf(-2.f*bf2f(xl)), myl=f2bf(-2.f*bf2f(yl)), mzl=f2bf(-2.f*bf2f(zl));
        slots[0]=mxh; slots[1]=myh; slots[2]=mzh;
        slots[3]=mxh; slots[4]=myh; slots[5]=mzh;
        slots[6]=mxl; slots[7]=myl; slots[8]=mzl;
        slots[9]=mxl; slots[10]=myl; slots[11]=mzl;
        slots[12]=sh;  slots[13]=sm;  slots[14]=sl;
        slots[15]=one; slots[16]=one; slots[17]=one;
    }

    int kbase = (lane >> 4) * 8;
    unsigned short v[8];
    #pragma unroll
    for (int j = 0; j < 8; ++j) {
        int k = kbase + j;
        v[j] = (k < 18) ? slots[k] : (unsigned short)0;
    }
    uint4 w;
    w.x = (unsigned)v[0] | ((unsigned)v[1] << 16);
    w.y = (unsigned)v[2] | ((unsigned)v[3] << 16);
    w.z = (unsigned)v[4] | ((unsigned)v[5] << 16);
    w.w = (unsigned)v[6] | ((unsigned)v[7] << 16);
    unsigned short* pan = whichB ? bpan : apan;
    uint4* dst = (uint4*)pan + (((size_t)n * NTILES + tile) * 64 + lane);
    *dst = w;
}

// MFMA selects the candidate pair (packed-key min3_u32 fold); the epilogue
// recomputes the captured pair's d^2 EXACTLY in fp32 from the raw clouds.
// => every stored value is a genuine pairwise distance (output>=ref-1e-4).
__global__ __launch_bounds__(256, 4) void chamfer_min_mfma(
    const float* __restrict__ cA, const float* __restrict__ cB,
    const unsigned short* __restrict__ apan, const unsigned short* __restrict__ bpan,
    unsigned int* __restrict__ minsdir /* [NBATCH][NPTS] for this dir */)
{
    int bid = blockIdx.x;
    const int jc  = bid & (JCH - 1);  bid >>= 4;
    const int mb  = bid & (MB - 1);   bid >>= 5;
    const int n   = bid;              // 0..1

    const int lane = threadIdx.x & 63;
    const int wv   = threadIdx.x >> 6;
    const int col  = lane & 15;

    const unsigned short* Abase = apan + (size_t)n * NTILES * 512;
    const unsigned short* Bbase = bpan + (size_t)n * NTILES * 512;

    const int mt0 = mb * (4 * MW) + wv * MW;

    s16x8 afrag[MW];
    #pragma unroll
    for (int m = 0; m < MW; ++m)
        afrag[m] = *(const s16x8*)(Abase + (size_t)(mt0 + m) * 512 + lane * 8);

    unsigned key[MW][4];
    #pragma unroll
    for (int m = 0; m < MW; ++m)
        #pragma unroll
        for (int r = 0; r < 4; ++r) key[m][r] = 0xFFFFFFFFu;

    const f32x4 czero = {0.f, 0.f, 0.f, 0.f};

    const unsigned short* bp = Bbase + (size_t)(jc * NT_PER) * 512 + lane * 8;
    s16x8 b0 = *(const s16x8*)(bp);
    s16x8 b1 = *(const s16x8*)(bp + 512);

    for (int t = 0; t < NT_PER; t += 2) {
        s16x8 nb0 = b0, nb1 = b1;
        if (t + 2 < NT_PER) {
            nb0 = *(const s16x8*)(bp + (size_t)(t + 2) * 512);
            nb1 = *(const s16x8*)(bp + (size_t)(t + 3) * 512);
        }
        const unsigned i0 = (unsigned)((t << 4) | col);
        const unsigned i1 = (unsigned)(((t + 1) << 4) | col);
        #pragma unroll
        for (int m = 0; m < MW; ++m) {
            f32x4 d0 = __builtin_amdgcn_mfma_f32_16x16x32_bf16(afrag[m], b0, czero, 0, 0, 0);
            f32x4 d1 = __builtin_amdgcn_mfma_f32_16x16x32_bf16(afrag[m], b1, czero, 0, 0, 0);
            #pragma unroll
            for (int r = 0; r < 4; ++r) {
                unsigned k0 = (__float_as_uint(d0[r]) & 0xFFFFFC00u) | i0;  // v_and_or_b32
                unsigned k1 = (__float_as_uint(d1[r]) & 0xFFFFFC00u) | i1;
                asm("v_min3_u32 %0, %1, %2, %3"
                    : "=v"(key[m][r]) : "v"(key[m][r]), "v"(k0), "v"(k1));
            }
        }
        b0 = nb0; b1 = nb1;
    }

    // Exact rescue: decode argmin b-index, recompute d^2 in fp32, reduce.
    const float* ca = cA + (size_t)n * NPTS * 3;
    const float* cb = cB + (size_t)n * NPTS * 3;
    const int jbase = jc * (NT_PER * 16);   // jc*1024

    #pragma unroll
    for (int m = 0; m < MW; ++m) {
        const int ia_base = (mt0 + m) * 16 + (lane >> 4) * 4;  // D: row=(lane>>4)*4+r [m89]
        #pragma unroll
        for (int r = 0; r < 4; ++r) {
            int jb = jbase + (int)(key[m][r] & 0x3FFu);
            const float* aq = ca + (size_t)(ia_base + r) * 3;
            const float* bq = cb + (size_t)jb * 3;
            float dx = aq[0] - bq[0];
            float dy = aq[1] - bq[1];
            float dz = aq[2] - bq[2];
            float d2 = fmaf(dx, dx, fmaf(dy, dy, dz * dz));   // exact fp32, >= 0
            d2 = fminf(d2, __shfl_xor(d2, 1, 64));
            d2 = fminf(d2, __shfl_xor(d2, 2, 64));
            d2 = fminf(d2, __shfl_xor(d2, 4, 64));
            d2 = fminf(d2, __shfl_xor(d2, 8, 64));
            if (col == 0)
                atomicMin(&minsdir[(size_t)n * NPTS + ia_base + r], __float_as_uint(d2));
        }
    }
}

// out[n] = mean_i min_a2b + mean_j min_b2a  (P1 == P2 so one divide).
__global__ __launch_bounds__(256) void chamfer_out(
    const unsigned int* __restrict__ mins, float* __restrict__ out)
{
    int n = blockIdx.x;
    float acc = 0.0f;
    for (int i = threadIdx.x; i < NPTS; i += 256) {
        acc += __uint_as_float(mins[(0 * NBATCH + n) * NPTS + i]);
        acc += __uint_as_float(mins[(1 * NBATCH + n) * NPTS + i]);
    }
    for (int off = 32; off > 0; off >>= 1) acc += __shfl_down(acc, off, 64);
    __shared__ float sm[4];
    int wv = threadIdx.x >> 6, ln = threadIdx.x & 63;
    if (ln == 0) sm[wv] = acc;
    __syncthreads();
    if (threadIdx.x == 0)
        out[n] = (sm[0] + sm[1] + sm[2] + sm[3]) / (float)NPTS;
}

extern "C" void kernel_launch(void* const* d_in, const int* in_sizes, int n_in,
                              void* d_out, int out_size, void* d_ws, size_t ws_size,
                              hipStream_t stream)
{
    const float* c1 = (const float*)d_in[0];
    const float* c2 = (const float*)d_in[1];
    float* out = (float*)d_out;

    char* ws = (char*)d_ws;
    // mins FIRST (low, proven region): 256 KiB. Panels after: 2 MiB + 2 MiB.
    unsigned int*   mins = (unsigned int*)ws;
    unsigned short* apan = (unsigned short*)(ws + (size_t)(2 * NBATCH * NPTS) * 4);
    unsigned short* bpan = apan + (size_t)NBATCH * NTILES * 512;
    // total footprint: 256 KiB + 4 MiB = 4.4375 MiB

    // init mins to a huge positive float (0x7f7f7f7f both as uint and float)
    hipMemsetAsync(mins, 0x7F, (size_t)2 * NBATCH * NPTS * sizeof(unsigned int), stream);

    // dir 0: A = cloud1, B = cloud2
    pack_panels<<<(1 << 18) / 256, 256, 0, stream>>>(c1, c2, apan, bpan);
    chamfer_min_mfma<<<NBATCH * MB * JCH, 256, 0, stream>>>(
        c1, c2, apan, bpan, mins + 0 * NBATCH * NPTS);
    // dir 1: A = cloud2, B = cloud1 (panels reused; same-stream serialization)
    pack_panels<<<(1 << 18) / 256, 256, 0, stream>>>(c2, c1, apan, bpan);
    chamfer_min_mfma<<<NBATCH * MB * JCH, 256, 0, stream>>>(
        c2, c1, apan, bpan, mins + 1 * NBATCH * NPTS);

    chamfer_out<<<NBATCH, 256, 0, stream>>>(mins, out);
}

// Round 9
// 108.701 us; speedup vs baseline: 1.5854x; 1.5854x over previous
//
#include <hip/hip_runtime.h>

#define NBATCH 2
#define NPTS   16384
#define TPTS   32                      // points per MFMA tile (32x32x16)
#define NTILES (NPTS / TPTS)           // 512
#define JCH    16                      // col-chunks per batch
#define NT_PER (NTILES / JCH)          // 32 col-tiles per chunk (1024 cols)
#define MB     (NPTS / 128)            // 128 row-blocks (block = 4 waves x 32 rows)

typedef float f32x16 __attribute__((ext_vector_type(16)));
typedef short s16x8 __attribute__((ext_vector_type(8)));

__device__ __forceinline__ unsigned short f2bf(float f) {   // RTNE, finite inputs
    unsigned u = __float_as_uint(f);
    u += 0x7FFF + ((u >> 16) & 1);
    return (unsigned short)(u >> 16);
}
__device__ __forceinline__ float bf2f(unsigned short h) {
    return __uint_as_float((unsigned)h << 16);
}
__device__ __forceinline__ unsigned umin2(unsigned a, unsigned b) { return a < b ? a : b; }

// K=16 panels for 32x32x16 bf16 MFMA. Rows = cloud1, cols = cloud2.
// A slots: [ah(3) | al(3) | ah(3) | 1 1 | sqa_h sqa_l | 1 | 0 0]
// B slots: [-2bh(3)| -2bh(3)| -2bl(3)| sqb_h sqb_l | 1 1 | 1 | 0 0]
// dot = 1 + sqa + sqb - 2(ah+al)·bh - 2ah·bl  = 1 + d^2 + err, |err| <~ 1e-4
// (+1 bias keeps all key values positive; rescue recomputes exactly anyway)
__global__ __launch_bounds__(256) void pack_panels(
    const float* __restrict__ c1, const float* __restrict__ c2,
    unsigned short* __restrict__ apan, unsigned short* __restrict__ bpan)
{
    int tid = blockIdx.x * 256 + threadIdx.x;   // 2^17 threads
    int lane = tid & 63;
    int tile = (tid >> 6) & (NTILES - 1);       // 9 bits
    int n    = (tid >> 15) & 1;
    int whichB = (tid >> 16) & 1;

    const float* src = whichB ? c2 : c1;

    int p = tile * TPTS + (lane & 31);
    const float* q = src + ((size_t)n * NPTS + p) * 3;
    float x = q[0], y = q[1], z = q[2];

    unsigned short xh = f2bf(x), yh = f2bf(y), zh = f2bf(z);
    unsigned short xl = f2bf(x - bf2f(xh)), yl = f2bf(y - bf2f(yh)), zl = f2bf(z - bf2f(zh));
    float sq = x * x + y * y + z * z;
    unsigned short sh = f2bf(sq);
    unsigned short sl = f2bf(sq - bf2f(sh));
    const unsigned short one = 0x3F80;

    unsigned short slots[16];
    if (!whichB) {
        slots[0]=xh;  slots[1]=yh;  slots[2]=zh;
        slots[3]=xl;  slots[4]=yl;  slots[5]=zl;
        slots[6]=xh;  slots[7]=yh;  slots[8]=zh;
        slots[9]=one; slots[10]=one;
        slots[11]=sh; slots[12]=sl;
        slots[13]=one; slots[14]=0; slots[15]=0;
    } else {
        unsigned short mxh=f2bf(-2.f*bf2f(xh)), myh=f2bf(-2.f*bf2f(yh)), mzh=f2bf(-2.f*bf2f(zh));
        unsigned short mxl=f2bf(-2.f*bf2f(xl)), myl=f2bf(-2.f*bf2f(yl)), mzl=f2bf(-2.f*bf2f(zl));
        slots[0]=mxh; slots[1]=myh; slots[2]=mzh;
        slots[3]=mxh; slots[4]=myh; slots[5]=mzh;
        slots[6]=mxl; slots[7]=myl; slots[8]=mzl;
        slots[9]=sh;  slots[10]=sl;
        slots[11]=one; slots[12]=one;
        slots[13]=one; slots[14]=0; slots[15]=0;
    }

    int j0 = (lane >> 5) * 8;
    uint4 w;
    w.x = (unsigned)slots[j0+0] | ((unsigned)slots[j0+1] << 16);
    w.y = (unsigned)slots[j0+2] | ((unsigned)slots[j0+3] << 16);
    w.z = (unsigned)slots[j0+4] | ((unsigned)slots[j0+5] << 16);
    w.w = (unsigned)slots[j0+6] | ((unsigned)slots[j0+7] << 16);
    unsigned short* pan = whichB ? bpan : apan;
    uint4* dst = (uint4*)pan + (((size_t)n * NTILES + tile) * 64 + lane);
    *dst = w;
}

// One 32x32 d^2 tile per MFMA. Both reductions from one pass, all final
// values EXACT (argmin-key select + fp32 recompute; R7-proven mechanism).
// NO LDS atomics: col partials use per-wave slices with plain stores.
// D layout (m74/m101 HW-verified): col=lane&31, row=(reg&3)+8*(reg>>2)+4*(lane>>5).
__global__ __launch_bounds__(256, 4) void chamfer32(
    const float* __restrict__ c1, const float* __restrict__ c2,
    const unsigned short* __restrict__ apan, const unsigned short* __restrict__ bpan,
    unsigned int* __restrict__ rowmins, unsigned int* __restrict__ colmins)
{
    __shared__ unsigned int ldscol[4][NT_PER * TPTS];   // 4 waves x 1024, 16 KiB

    int bid = blockIdx.x;
    const int jc = bid & (JCH - 1); bid >>= 4;
    const int mb = bid & (MB - 1);  bid >>= 7;
    const int n  = bid;

    const int lane   = threadIdx.x & 63;
    const int wv     = threadIdx.x >> 6;
    const int colw   = lane & 31;
    const int laneHi = lane >> 5;

    const int mt = mb * 4 + wv;   // this wave's row-tile (32 rows)

    s16x8 afrag = *(const s16x8*)(apan + ((size_t)(n * NTILES + mt) * 64 + lane) * 8);

    unsigned int rowlc[16];   // wave-local row id (7 bits) for col keys
    unsigned int kr[16];      // row-side keys: d2-bits | (t*32+colw)
    #pragma unroll
    for (int r = 0; r < 16; ++r) {
        rowlc[r] = (unsigned)(wv * 32 + (r & 3) + 8 * (r >> 2) + 4 * laneHi);
        kr[r] = 0xFFFFFFFFu;
    }

    f32x16 cz = {0.f,0.f,0.f,0.f,0.f,0.f,0.f,0.f,0.f,0.f,0.f,0.f,0.f,0.f,0.f,0.f};

    const unsigned short* bbase =
        bpan + ((size_t)(n * NTILES + jc * NT_PER) * 64 + lane) * 8;
    s16x8 b = *(const s16x8*)(bbase);
    unsigned int vidx = (unsigned)colw;    // t*32 + colw, incremented per tile

    for (int t = 0; t < NT_PER; ++t) {
        s16x8 bn = b;
        if (t + 1 < NT_PER) bn = *(const s16x8*)(bbase + (size_t)(t + 1) * 512);

        f32x16 d = __builtin_amdgcn_mfma_f32_32x32x16_bf16(afrag, b, cz, 0, 0, 0);

        unsigned int cmin = 0xFFFFFFFFu;
        #pragma unroll
        for (int r = 0; r < 16; ++r) {
            unsigned int bits = __float_as_uint(d[r]);
            kr[r] = umin2(kr[r], (bits & 0xFFFFFC00u) | vidx);       // row key
            cmin  = umin2(cmin,  (bits & 0xFFFFFF80u) | rowlc[r]);   // col key
        }
        cmin = umin2(cmin, (unsigned)__shfl_xor((int)cmin, 32, 64)); // fold lane halves
        if (lane < 32) ldscol[wv][t * 32 + colw] = cmin;             // plain store, 1 writer
        vidx += 32;
        b = bn;
    }

    const float* ca = c1 + (size_t)n * NPTS * 3;
    const float* cb = c2 + (size_t)n * NPTS * 3;

    // Row side: key-min across the 32 cols (lanes sharing laneHi), then ONE
    // exact rescue per row.
    #pragma unroll
    for (int r = 0; r < 16; ++r) {
        unsigned int k = kr[r];
        k = umin2(k, (unsigned)__shfl_xor((int)k, 1, 64));
        k = umin2(k, (unsigned)__shfl_xor((int)k, 2, 64));
        k = umin2(k, (unsigned)__shfl_xor((int)k, 4, 64));
        k = umin2(k, (unsigned)__shfl_xor((int)k, 8, 64));
        k = umin2(k, (unsigned)__shfl_xor((int)k, 16, 64));
        if (colw == 0) {
            int idx  = (int)(k & 1023u);
            int colg = (jc * NT_PER) * 32 + idx;          // = (jc*32+t)*32+cw
            int rowg = mt * 32 + (r & 3) + 8 * (r >> 2) + 4 * laneHi;
            float dx = ca[rowg * 3 + 0] - cb[colg * 3 + 0];
            float dy = ca[rowg * 3 + 1] - cb[colg * 3 + 1];
            float dz = ca[rowg * 3 + 2] - cb[colg * 3 + 2];
            float d2 = fmaf(dx, dx, fmaf(dy, dy, dz * dz));
            atomicMin(&rowmins[(size_t)n * NPTS + rowg], __float_as_uint(d2));
        }
    }

    // Col side: merge the 4 wave slices, ONE exact rescue per column slot.
    __syncthreads();
    for (int s = threadIdx.x; s < NT_PER * TPTS; s += 256) {
        unsigned int k = umin2(umin2(ldscol[0][s], ldscol[1][s]),
                               umin2(ldscol[2][s], ldscol[3][s]));
        int rowg = mb * 128 + (int)(k & 127u);
        int colg = jc * (NT_PER * TPTS) + s;
        float dx = ca[rowg * 3 + 0] - cb[colg * 3 + 0];
        float dy = ca[rowg * 3 + 1] - cb[colg * 3 + 1];
        float dz = ca[rowg * 3 + 2] - cb[colg * 3 + 2];
        float d2 = fmaf(dx, dx, fmaf(dy, dy, dz * dz));
        atomicMin(&colmins[(size_t)n * NPTS + colg], __float_as_uint(d2));
    }
}

// out[n] = mean_i min_a2b + mean_j min_b2a  (P1 == P2 so one divide).
__global__ __launch_bounds__(256) void chamfer_out(
    const unsigned int* __restrict__ mins, float* __restrict__ out)
{
    int n = blockIdx.x;
    float acc = 0.0f;
    for (int i = threadIdx.x; i < NPTS; i += 256) {
        acc += __uint_as_float(mins[(0 * NBATCH + n) * NPTS + i]);
        acc += __uint_as_float(mins[(1 * NBATCH + n) * NPTS + i]);
    }
    for (int off = 32; off > 0; off >>= 1) acc += __shfl_down(acc, off, 64);
    __shared__ float sm[4];
    int wv = threadIdx.x >> 6, ln = threadIdx.x & 63;
    if (ln == 0) sm[wv] = acc;
    __syncthreads();
    if (threadIdx.x == 0)
        out[n] = (sm[0] + sm[1] + sm[2] + sm[3]) / (float)NPTS;
}

extern "C" void kernel_launch(void* const* d_in, const int* in_sizes, int n_in,
                              void* d_out, int out_size, void* d_ws, size_t ws_size,
                              hipStream_t stream)
{
    const float* c1 = (const float*)d_in[0];
    const float* c2 = (const float*)d_in[1];
    float* out = (float*)d_out;

    char* ws = (char*)d_ws;
    // mins at base (region proven writable in R1-R7): 256 KiB.
    unsigned int*   mins = (unsigned int*)ws;
    unsigned short* apan = (unsigned short*)(ws + (size_t)(2 * NBATCH * NPTS) * 4);
    unsigned short* bpan = apan + (size_t)NBATCH * NTILES * 512;
    // footprint: 256 KiB + 1 MiB + 1 MiB = 2.25 MiB (< R7's proven 4.44 MiB)

    unsigned int* rowmins = mins;                          // cloud1 -> cloud2
    unsigned int* colmins = mins + (size_t)NBATCH * NPTS;  // cloud2 -> cloud1

    hipMemsetAsync(mins, 0x7F, (size_t)2 * NBATCH * NPTS * sizeof(unsigned int), stream);

    pack_panels<<<(1 << 17) / 256, 256, 0, stream>>>(c1, c2, apan, bpan);
    chamfer32<<<NBATCH * MB * JCH, 256, 0, stream>>>(c1, c2, apan, bpan, rowmins, colmins);
    chamfer_out<<<NBATCH, 256, 0, stream>>>(mins, out);
}